// Round 17
// baseline (185.092 us; speedup 1.0000x reference)
//
#include <hip/hip_runtime.h>
#include <hip/hip_bf16.h>

typedef int   i32x4  __attribute__((ext_vector_type(4)));
typedef int   i32x8  __attribute__((ext_vector_type(8)));
typedef float f32x16 __attribute__((ext_vector_type(16)));

__device__ inline void gload_lds16(const void* g, void* l) {
  __builtin_amdgcn_global_load_lds((const __attribute__((address_space(1))) void*)g,
                                   (__attribute__((address_space(3))) void*)l, 16, 0, 0);
}
__device__ inline void gload_lds4(const void* g, void* l) {
  __builtin_amdgcn_global_load_lds((const __attribute__((address_space(1))) void*)g,
                                   (__attribute__((address_space(3))) void*)l, 4, 0, 0);
}
__device__ inline i32x8 pad8(i32x4 v) {
  i32x8 r;
  r[0] = v[0]; r[1] = v[1]; r[2] = v[2]; r[3] = v[3];
  r[4] = 0; r[5] = 0; r[6] = 0; r[7] = 0;
  return r;
}

// ------------- Fused quantization: Hadamard(32) rotate + MXFP4 pack (x and w in one grid) ---
// At HBM roofline (~228MB vs ~36us floor) - unchanged since R7.
__global__ __launch_bounds__(256) void quant_fused(const float* __restrict__ x,
                                                   const float* __restrict__ wt,
                                                   unsigned char* __restrict__ xq,
                                                   unsigned char* __restrict__ xsc,
                                                   unsigned char* __restrict__ wq,
                                                   unsigned char* __restrict__ wsc,
                                                   const float* __restrict__ ags,
                                                   const float* __restrict__ wgs,
                                                   int xg, int Mrows, int Nrows, int kg) {
  const int first = blockIdx.x * 256;
  const bool isX = first < xg;
  const float* in        = isX ? x   : wt;
  unsigned char* outq    = isX ? xq  : wq;
  unsigned char* outsc   = isX ? xsc : wsc;
  const float gs         = isX ? ags[0] : wgs[0];
  const int rows         = isX ? Mrows : Nrows;
  const int base         = isX ? first : first - xg;
  const int g = base + threadIdx.x;
  const int r = g / kg, j = g - r * kg;

  float t[32];
  const float4* p4 = (const float4*)(in + (size_t)g * 32);
#pragma unroll
  for (int i = 0; i < 8; ++i) {
    float4 v4 = p4[i];
    t[4 * i + 0] = v4.x; t[4 * i + 1] = v4.y;
    t[4 * i + 2] = v4.z; t[4 * i + 3] = v4.w;
  }
#pragma unroll
  for (int s = 0; s < 5; ++s) {
    const int hh = 1 << s;
#pragma unroll
    for (int i = 0; i < 32; ++i) {
      if ((i & hh) == 0) {
        float a = t[i], b = t[i + hh];
        t[i] = a + b;
        t[i + hh] = a - b;
      }
    }
  }

  const float c = 0.17677669529663687f;  // 32^-0.5
  float v[32];
  float am = 0.0f;
#pragma unroll
  for (int i = 0; i < 32; ++i) {
    float vi = (t[i] * c) * gs;
    v[i] = vi;
    am = fmaxf(am, fabsf(vi));
  }

  float a6 = am / 6.0f;
  int ex;
  float mant = frexpf(a6, &ex);
  int e = (mant == 0.5f) ? ex - 1 : ex;  // exact ceil(log2(a6))
  if (e < -127) e = -127;
  if (e > 127) e = 127;
  float inv_s = ldexpf(1.0f, -e);

  unsigned int dw[4] = {0u, 0u, 0u, 0u};
#pragma unroll
  for (int i = 0; i < 32; ++i) {
    float u = v[i] * inv_s;
    float au = fabsf(u);
    int idx = (au > 0.25f) + (au > 0.75f) + (au > 1.25f) + (au > 1.75f)
            + (au > 2.5f) + (au > 3.5f) + (au > 5.0f);
    int code = idx | ((u < 0.0f) ? 8 : 0);
    dw[i >> 3] |= (unsigned)code << ((i & 7) * 4);
  }
  i32x4 packed;
  packed[0] = (int)dw[0]; packed[1] = (int)dw[1];
  packed[2] = (int)dw[2]; packed[3] = (int)dw[3];
  *(i32x4*)(outq + (size_t)r * ((size_t)kg * 16) + (size_t)j * 16) = packed;

  // scale byte: [superstep s(256k)][row][8B], byte p = h*4 + kk for block j0 = 2*kk + h
  int s = j >> 3, j0 = j & 7;
  int p = ((j0 & 1) << 2) | (j0 >> 1);
  if (kg == 128) {
    __shared__ unsigned char sl[256];  // [16 steps][2 rows][8B]
    sl[(s << 4) | ((r & 1) << 3) | p] = (unsigned char)(e + 127);
    __syncthreads();
    if (threadIdx.x < 64) {
      int si = threadIdx.x >> 2, wd = threadIdx.x & 3;
      unsigned int vv = *(const unsigned int*)&sl[(si << 4) | (wd << 2)];
      size_t r0 = (size_t)(base / 128);
      *(unsigned int*)(outsc + ((size_t)si * rows + r0) * 8 + (wd << 2)) = vv;
    }
  } else {
    outsc[((size_t)s * rows + r) * 8 + p] = (unsigned char)(e + 127);
  }
}

// -------- 256x128 MX-FP4 GEMM, BK=128, 512 thr (8 waves = 4M x 2N of 64x64), 2 blk/CU ----
// R11's race-free single-phase skeleton at 4 waves/SIMD with 1.0 ds_read/MFMA.
// Per tile t (buf p=t&1): {8 ds_read_b128 + 4 b32 -> lgkm0 -> barrier [all buf-p reads
// done] -> stage set(t+2)->buf[p] -> 8 MFMA (opsel=(t&1)*2+kk) -> VM4(even)/VM3(odd)
// [drains set(t+1) for both wave classes] -> barrier}. Scales per 256-K superstep,
// dbuf, staged with even tiles (waves 0-3 also carry BSC -> class counts {5|4}/3).

#define STAGE_A(kt, jj, bf) do {                                                     \
    int _row = 16 * w + 128 * (jj) + (l >> 2);                                       \
    const unsigned char* _s = Ab + (size_t)_row * KB2 + (size_t)(kt) * 64            \
                              + (size_t)csw * 16;                                    \
    gload_lds16(_s, (unsigned char*)&lds[bf][0] + (jj) * 8192 + (w << 10));          \
  } while (0)

#define STAGE_B(kt, bf) do {                                                         \
    int _row = 16 * w + (l >> 2);                                                    \
    const unsigned char* _s = Bb + (size_t)_row * KB2 + (size_t)(kt) * 64            \
                              + (size_t)csw * 16;                                    \
    gload_lds16(_s, (unsigned char*)&lds[bf][16384] + (w << 10));                    \
  } while (0)

// even-tile stage: A(2) + B(1) + ASC(1 all waves) + BSC(1, waves 0-3) = 5|4 VMEM
#define STAGESET_E(kt, bf, sbuf) do {                                                \
    STAGE_A(kt, 0, bf); STAGE_A(kt, 1, bf); STAGE_B(kt, bf);                         \
    gload_lds4(AscG + ((size_t)(sskt) * M + brow) * 8 + (tid << 2),                  \
               (unsigned char*)&asc[sbuf][0] + (w << 8));                            \
    if (w < 4)                                                                       \
      gload_lds4(BscG + ((size_t)(sskt) * N + bcol) * 8 + (tid << 2),                \
                 (unsigned char*)&bsc[sbuf][0] + (w << 8));                          \
  } while (0)

// odd-tile stage: A(2) + B(1) = 3 VMEM
#define STAGESET_O(kt, bf) do {                                                      \
    STAGE_A(kt, 0, bf); STAGE_A(kt, 1, bf); STAGE_B(kt, bf);                         \
  } while (0)

#define READFRAGS(bf, ssel) do {                                                     \
    const unsigned char* _bbase = &lds[bf][16384];                                   \
    _Pragma("unroll")                                                                \
    for (int nt = 0; nt < 2; ++nt) {                                                 \
      int row = wn * 64 + nt * 32 + (l & 31);                                        \
      int xr = row & 3;                                                              \
      _Pragma("unroll")                                                              \
      for (int kk = 0; kk < 2; ++kk)                                                 \
        bfr[nt][kk] = *(const i32x4*)(_bbase + row * 64 + (((kk * 2 + h) ^ xr) << 4)); \
      sb[nt] = *(const int*)((const unsigned char*)&bsc[ssel][0] + row * 8 + h * 4); \
    }                                                                                \
    const unsigned char* _abase = &lds[bf][0];                                       \
    _Pragma("unroll")                                                                \
    for (int mt = 0; mt < 2; ++mt) {                                                 \
      int row = wm * 64 + mt * 32 + (l & 31);                                        \
      int xr = row & 3;                                                              \
      _Pragma("unroll")                                                              \
      for (int kk = 0; kk < 2; ++kk)                                                 \
        af[mt][kk] = *(const i32x4*)(_abase + row * 64 + (((kk * 2 + h) ^ xr) << 4)); \
      sa[mt] = *(const int*)((const unsigned char*)&asc[ssel][0] + row * 8 + h * 4); \
    } } while (0)

#define MF1(mt, nt, kk, OP)                                                          \
  acc[mt][nt] = __builtin_amdgcn_mfma_scale_f32_32x32x64_f8f6f4(                     \
      pad8(af[mt][kk]), pad8(bfr[nt][kk]), acc[mt][nt], 4, 4, OP, sa[mt], OP, sb[nt]);

#define MFMAQ8(P) do {                                                               \
    __builtin_amdgcn_s_setprio(1);                                                   \
    MF1(0, 0, 0, P) MF1(0, 1, 0, P) MF1(1, 0, 0, P) MF1(1, 1, 0, P)                  \
    MF1(0, 0, 1, P + 1) MF1(0, 1, 1, P + 1) MF1(1, 0, 1, P + 1) MF1(1, 1, 1, P + 1)  \
    __builtin_amdgcn_s_setprio(0);                                                   \
  } while (0)

#define DRAIN_THEN_BAR() do {                                                        \
    asm volatile("s_waitcnt lgkmcnt(0)" ::: "memory");                               \
    __builtin_amdgcn_sched_barrier(0);                                               \
    __builtin_amdgcn_s_barrier();                                                    \
  } while (0)

#define ENDP() __builtin_amdgcn_s_barrier()
#define VM4()  asm volatile("s_waitcnt vmcnt(4)" ::: "memory")
#define VM3()  asm volatile("s_waitcnt vmcnt(3)" ::: "memory")

__global__ __launch_bounds__(512, 4) void gemm256x128_fp4(const unsigned char* __restrict__ Aq,
                                                          const unsigned char* __restrict__ Bq,
                                                          const unsigned char* __restrict__ AscG,
                                                          const unsigned char* __restrict__ BscG,
                                                          float* __restrict__ C,
                                                          const float* __restrict__ bias,
                                                          const float* __restrict__ gsx,
                                                          const float* __restrict__ gsw,
                                                          int M, int N, int K) {
  __shared__ __align__(16) unsigned char lds[2][24576];  // [buf][A:256x64B | B:128x64B]
  __shared__ __align__(16) unsigned char asc[2][2048];   // [sbuf][256 rows x 8B]
  __shared__ __align__(16) unsigned char bsc[2][1024];   // [sbuf][128 rows x 8B]

  const int tid = threadIdx.x;
  const int w = tid >> 6, l = tid & 63;
  const int wm = w >> 1, wn = w & 1;   // 4M x 2N waves of 64x64
  const int h = l >> 5;
  const int csw = (l & 3) ^ ((l >> 2) & 3);  // inverse-swizzled source chunk (row&3)
  const int KB2 = K >> 1;                    // bytes per row

  // T1 + L2 supertiling: XCD band + 8x8 supertiles (proven FETCH reducer).
  const int ntn = N >> 7;              // 128-wide col tiles
  const int nwg = gridDim.x;
  int r_t, c_t;
  {
    int bid = blockIdx.x;
    if ((nwg & 7) == 0) {
      int x = bid & 7, o = bid >> 3, cpx = nwg >> 3;
      int rpx = cpx / ntn;
      if ((ntn & 7) == 0 && rpx > 0 && (cpx % ntn) == 0) {
        int g8 = o & 7, rr = (o >> 3) % rpx, ss = o / (8 * rpx);
        r_t = x * rpx + rr;
        c_t = ss * 8 + g8;
      } else {
        int lin = x * cpx + o;
        r_t = lin / ntn; c_t = lin % ntn;
      }
    } else {
      r_t = bid / ntn; c_t = bid % ntn;
    }
  }
  const size_t brow = (size_t)r_t * 256;
  const size_t bcol = (size_t)c_t * 128;

  const unsigned char* Ab = Aq + brow * (size_t)KB2;
  const unsigned char* Bb = Bq + bcol * (size_t)KB2;

  f32x16 acc[2][2];
#pragma unroll
  for (int m = 0; m < 2; ++m)
#pragma unroll
    for (int n = 0; n < 2; ++n)
#pragma unroll
      for (int r = 0; r < 16; ++r) acc[m][n][r] = 0.0f;

  i32x4 af[2][2], bfr[2][2];
  int sa[2], sb[2];

  const int nkt = K / 128;       // 32 tiles
  const int nss = K / 256;       // 16 scale supersteps

  // Prologue: set(0) (even: data+scales ss0) -> buf0; set(1) (odd) -> buf1.
  // VM3 drains set(0) for both wave classes; keeps set(1) (3).
  {
    const int sskt = 0;
    STAGESET_E(0, 0, 0);
  }
  STAGESET_O(1, 1);
  VM3();
  __builtin_amdgcn_s_barrier();

  for (int s = 0; s < nkt / 2; ++s) {
    const int t = 2 * s;
    const int t2 = (t + 2 < nkt) ? t + 2 : nkt - 1;  // tail: stages a buffer never read again
    const int t3 = (t + 3 < nkt) ? t + 3 : nkt - 1;
    const int ssel = s & 1;
    const int sskt = (s + 1 < nss) ? s + 1 : nss - 1;

    // even tile t: reads buf0 + scales[ssel]; stage set(t+2)+scales(ss+1)->buf0/sbuf[ssel^1]
    READFRAGS(0, ssel);
    DRAIN_THEN_BAR();
    STAGESET_E(t2, 0, ssel ^ 1);
    __builtin_amdgcn_sched_barrier(0);
    MFMAQ8(0);
    VM4();                       // drains set(t+1); keeps set(t+2) (4|5-1 per class)
    ENDP();

    // odd tile t+1: reads buf1 + scales[ssel]; stage set(t+3)->buf1
    READFRAGS(1, ssel);
    DRAIN_THEN_BAR();
    STAGESET_O(t3, 1);
    __builtin_amdgcn_sched_barrier(0);
    MFMAQ8(2);
    VM3();                       // drains set(t+2) incl scales; keeps set(t+3) (3)
    ENDP();
  }

  const float inv = 1.0f / (gsx[0] * gsw[0]);
#pragma unroll
  for (int nt = 0; nt < 2; ++nt) {
    const int col = (int)bcol + wn * 64 + nt * 32 + (l & 31);
    const float bv = bias[col];
#pragma unroll
    for (int mt = 0; mt < 2; ++mt) {
      const size_t rbase = brow + (size_t)(wm * 64 + mt * 32 + 4 * h);
#pragma unroll
      for (int r = 0; r < 16; ++r) {
        const size_t row = rbase + (r & 3) + 8 * (r >> 2);
        C[row * (size_t)N + col] = acc[mt][nt][r] * inv + bv;
      }
    }
  }
}

extern "C" void kernel_launch(void* const* d_in, const int* in_sizes, int n_in,
                              void* d_out, int out_size, void* d_ws, size_t ws_size,
                              hipStream_t stream) {
  const float* x    = (const float*)d_in[0];
  const float* wgt  = (const float*)d_in[1];
  const float* bias = (const float*)d_in[2];
  const float* wgs  = (const float*)d_in[4];
  const float* ags  = (const float*)d_in[5];

  const int N = in_sizes[2];            // 4096
  const int K = in_sizes[1] / N;        // 4096
  const int M = in_sizes[0] / K;        // 8192
  const int kg = K / 32;                // 128

  unsigned char* aq  = (unsigned char*)d_ws;
  unsigned char* bq  = aq + (size_t)M * (K / 2);
  unsigned char* asc = bq + (size_t)N * (K / 2);
  unsigned char* bsc = asc + (size_t)M * kg;

  const int xg = in_sizes[0] / 32;
  const int wg = in_sizes[1] / 32;
  quant_fused<<<dim3((xg + wg) / 256), dim3(256), 0, stream>>>(
      x, wgt, aq, asc, bq, bsc, ags, wgs, xg, M, N, kg);

  dim3 grid((M / 256) * (N / 128));
  gemm256x128_fp4<<<grid, dim3(512), 0, stream>>>(aq, bq, asc, bsc, (float*)d_out, bias,
                                                  ags, wgs, M, N, K);
}